// Round 6
// baseline (1664.517 us; speedup 1.0000x reference)
//
#include <hip/hip_runtime.h>

#define DEV __device__ __forceinline__

// ===== DIAGNOSTIC ROUND: internal repeat loops make every kernel visible =====
// in rocprof top-5 (fills are ~158us; each kernel x REPS must exceed that).
// All kernels are idempotent so reps are correctness-neutral. dur/REPS = truth.
#define PRE_REPS  4
#define DUAL_REPS 3
#define SAMP_REPS 6
#define FIN_REPS  8

typedef short bf16x8 __attribute__((ext_vector_type(8)));
typedef float f32x4 __attribute__((ext_vector_type(4)));
typedef unsigned int u32;
typedef __attribute__((address_space(1))) const u32* gas_ptr;
typedef __attribute__((address_space(3))) u32* las_ptr;

// ---------- helpers ----------
DEV short f2bf(float f) {
  union { float f; unsigned u; } un; un.f = f;
  unsigned r = un.u + 0x7FFFu + ((un.u >> 16) & 1u);  // RNE
  return (short)(r >> 16);
}
DEV float bf2f(unsigned short s) {
  union { unsigned u; float f; } un;
  un.u = ((unsigned)s) << 16;
  return un.f;
}
DEV void gload16(const short* g, short* l) {
  __builtin_amdgcn_global_load_lds((gas_ptr)g, (las_ptr)l, 16, 0, 0);
}
DEV float hsum4(float4 v) { return v.x + v.y + v.z + v.w; }

// ---------- LayerNorm row (wave-per-row, barrier-free) ----------
DEV void ln_row4(const float* __restrict__ x, const float* __restrict__ w,
                 const float* __restrict__ b, short* __restrict__ y,
                 const int rb) {
  const int wv = threadIdx.x >> 6, lane = threadIdx.x & 63;
  const int row = rb * 4 + wv;
  const float* xr = x + (size_t)row * 768;
  float4 v0 = *(const float4*)(xr + lane * 4);
  float4 v1 = *(const float4*)(xr + 256 + lane * 4);
  float4 v2 = *(const float4*)(xr + 512 + lane * 4);
  float s = hsum4(v0) + hsum4(v1) + hsum4(v2);
  #pragma unroll
  for (int off = 32; off > 0; off >>= 1) s += __shfl_xor(s, off, 64);
  const float mu = s * (1.f / 768.f);
  float4 d0 = make_float4(v0.x - mu, v0.y - mu, v0.z - mu, v0.w - mu);
  float4 d1 = make_float4(v1.x - mu, v1.y - mu, v1.z - mu, v1.w - mu);
  float4 d2 = make_float4(v2.x - mu, v2.y - mu, v2.z - mu, v2.w - mu);
  float vs = d0.x * d0.x + d0.y * d0.y + d0.z * d0.z + d0.w * d0.w +
             d1.x * d1.x + d1.y * d1.y + d1.z * d1.z + d1.w * d1.w +
             d2.x * d2.x + d2.y * d2.y + d2.z * d2.z + d2.w * d2.w;
  #pragma unroll
  for (int off = 32; off > 0; off >>= 1) vs += __shfl_xor(vs, off, 64);
  const float rs = rsqrtf(vs * (1.f / 768.f) + 1e-6f);
  const float4 w0 = *(const float4*)(w + lane * 4);
  const float4 w1 = *(const float4*)(w + 256 + lane * 4);
  const float4 w2 = *(const float4*)(w + 512 + lane * 4);
  const float4 b0 = *(const float4*)(b + lane * 4);
  const float4 b1 = *(const float4*)(b + 256 + lane * 4);
  const float4 b2 = *(const float4*)(b + 512 + lane * 4);
  unsigned short* yr = (unsigned short*)y + (size_t)row * 768;
  ushort4 o;
  o.x = (unsigned short)f2bf(d0.x * rs * w0.x + b0.x);
  o.y = (unsigned short)f2bf(d0.y * rs * w0.y + b0.y);
  o.z = (unsigned short)f2bf(d0.z * rs * w0.z + b0.z);
  o.w = (unsigned short)f2bf(d0.w * rs * w0.w + b0.w);
  *(ushort4*)(yr + lane * 4) = o;
  o.x = (unsigned short)f2bf(d1.x * rs * w1.x + b1.x);
  o.y = (unsigned short)f2bf(d1.y * rs * w1.y + b1.y);
  o.z = (unsigned short)f2bf(d1.z * rs * w1.z + b1.z);
  o.w = (unsigned short)f2bf(d1.w * rs * w1.w + b1.w);
  *(ushort4*)(yr + 256 + lane * 4) = o;
  o.x = (unsigned short)f2bf(d2.x * rs * w2.x + b2.x);
  o.y = (unsigned short)f2bf(d2.y * rs * w2.y + b2.y);
  o.z = (unsigned short)f2bf(d2.z * rs * w2.z + b2.z);
  o.w = (unsigned short)f2bf(d2.w * rs * w2.w + b2.w);
  *(ushort4*)(yr + 512 + lane * 4) = o;
}

DEV void pack_body(
    const float* __restrict__ w_val, const float* __restrict__ w_off,
    const float* __restrict__ w_aw, const float* __restrict__ w_out,
    const float* __restrict__ b_off, const float* __restrict__ b_aw,
    short* __restrict__ wT_val, short* __restrict__ wT_offaw,
    short* __restrict__ wT_out, float* __restrict__ bias_cat) {
  int g = (blockIdx.x - 25600) * 256 + threadIdx.x;
  bf16x8 v;
  if (g < 36864) {
    int n = g / 96, k0 = (g % 96) * 8;
    #pragma unroll
    for (int i = 0; i < 8; i++) v[i] = f2bf(w_val[(size_t)(k0 + i) * 384 + n]);
    *(bf16x8*)&wT_val[n * 768 + k0] = v;
    return;
  }
  g -= 36864;
  if (g < 27648) {
    int n = g / 96, k0 = (g % 96) * 8;
    #pragma unroll
    for (int i = 0; i < 8; i++) v[i] = f2bf(w_off[(size_t)(k0 + i) * 288 + n]);
    *(bf16x8*)&wT_offaw[n * 768 + k0] = v;
    return;
  }
  g -= 27648;
  if (g < 13824) {
    int n = g / 96, k0 = (g % 96) * 8;
    #pragma unroll
    for (int i = 0; i < 8; i++) v[i] = f2bf(w_aw[(size_t)(k0 + i) * 144 + n]);
    *(bf16x8*)&wT_offaw[(288 + n) * 768 + k0] = v;
    return;
  }
  g -= 13824;
  if (g < 7680) {
    int n = 432 + g / 96, k0 = (g % 96) * 8;
    #pragma unroll
    for (int i = 0; i < 8; i++) v[i] = 0;
    *(bf16x8*)&wT_offaw[n * 768 + k0] = v;
    return;
  }
  g -= 7680;
  if (g < 36864) {
    int n = g / 48, k0 = (g % 48) * 8;
    #pragma unroll
    for (int i = 0; i < 8; i++) v[i] = f2bf(w_out[(size_t)(k0 + i) * 768 + n]);
    *(bf16x8*)&wT_out[n * 384 + k0] = v;
    return;
  }
  g -= 36864;
  if (g < 512) { bias_cat[g] = (g < 288) ? b_off[g] : (g < 432 ? b_aw[g - 288] : 0.f); }
}

// ---------- fused pre-kernel: ln_kv + ln_q + weight pack ----------
__global__ __launch_bounds__(256) void fused_pre_kernel(
    const float* __restrict__ kv, const float* __restrict__ q,
    const float* __restrict__ ln2w, const float* __restrict__ ln2b,
    const float* __restrict__ ln1w, const float* __restrict__ ln1b,
    short* __restrict__ kvn, short* __restrict__ qn,
    const float* __restrict__ w_val, const float* __restrict__ w_off,
    const float* __restrict__ w_aw, const float* __restrict__ w_out,
    const float* __restrict__ b_off, const float* __restrict__ b_aw,
    short* __restrict__ wT_val, short* __restrict__ wT_offaw,
    short* __restrict__ wT_out, float* __restrict__ bias_cat) {
  const int bid = blockIdx.x;
  for (int rep = 0; rep < PRE_REPS; ++rep) {
    asm volatile("" ::: "memory");  // prevent cross-rep load hoisting
    if (bid < 21504) { ln_row4(kv, ln2w, ln2b, kvn, bid); }
    else if (bid < 25600) { ln_row4(q, ln1w, ln1b, qn, bid - 21504); }
    else {
      pack_body(w_val, w_off, w_aw, w_out, b_off, b_aw,
                wT_val, wT_offaw, wT_out, bias_cat);
    }
  }
}

// ---------- GEMM core: 128x128 tile, BK=32, 3-deep LDS pipeline ----------
// (identical to R5: XOR-swizzled LDS, vmcnt(8) steady state, lgkmcnt(0)
// before barrier2)
DEV void gemm_core(const short* __restrict__ A, const short* __restrict__ Wt,
                   const int K, const int row0, const int n0,
                   short* As, short* Bs, f32x4 acc[4][4]) {
  const int tid = threadIdx.x;
  const int wave = tid >> 6, lane = tid & 63;
  const int lr = lane & 15, quad = lane >> 4;
  const int wm = wave >> 1, wn = wave & 1;

  const short* gA[2]; const short* gB[2];
  int loA[2];
  #pragma unroll
  for (int rnd = 0; rnd < 2; rnd++) {
    int G = rnd * 256 + wave * 64 + lane;
    int line = G >> 3, pos = G & 7, x = pos ^ (line & 7);
    int r = line * 2 + (x >> 2), qk = (x & 3) * 8;
    gA[rnd] = A + (size_t)(row0 + r) * K + qk;
    gB[rnd] = Wt + (size_t)(n0 + r) * K + qk;
    loA[rnd] = (rnd * 256 + wave * 64) * 8;
  }

  int aOff[4], bOff[4];
  #pragma unroll
  for (int t4 = 0; t4 < 4; t4++) {
    int r = wm * 64 + t4 * 16 + lr;
    int pos = ((r & 1) * 4 + quad) ^ ((r >> 1) & 7);
    aOff[t4] = ((r >> 1) * 8 + pos) * 8;
    int rb = wn * 64 + t4 * 16 + lr;
    int posb = ((rb & 1) * 4 + quad) ^ ((rb >> 1) & 7);
    bOff[t4] = ((rb >> 1) * 8 + posb) * 8;
  }

  #pragma unroll
  for (int i = 0; i < 4; i++)
    #pragma unroll
    for (int j = 0; j < 4; j++)
      #pragma unroll
      for (int e = 0; e < 4; e++) acc[i][j][e] = 0.f;

  const int nt = K >> 5;
  #pragma unroll
  for (int pb = 0; pb < 2; pb++) {
    const int bb = pb * 4096;
    gload16(gA[0], As + bb + loA[0]);
    gload16(gA[1], As + bb + loA[1]);
    gload16(gB[0], Bs + bb + loA[0]);
    gload16(gB[1], Bs + bb + loA[1]);
    gA[0] += 32; gA[1] += 32; gB[0] += 32; gB[1] += 32;
  }

  int cur = 0;
  for (int t = 0; t < nt; ++t) {
    if (t + 2 < nt) {
      const int nb = (cur == 0 ? 2 : cur - 1) * 4096;  // (cur+2)%3
      gload16(gA[0], As + nb + loA[0]);
      gload16(gA[1], As + nb + loA[1]);
      gload16(gB[0], Bs + nb + loA[0]);
      gload16(gB[1], Bs + nb + loA[1]);
      gA[0] += 32; gA[1] += 32; gB[0] += 32; gB[1] += 32;
      asm volatile("s_waitcnt vmcnt(8)" ::: "memory");
    } else if (t + 1 < nt) {
      asm volatile("s_waitcnt vmcnt(4)" ::: "memory");
    } else {
      asm volatile("s_waitcnt vmcnt(0)" ::: "memory");
    }
    asm volatile("s_barrier" ::: "memory");
    const int cb = cur * 4096;
    bf16x8 av[4], bv[4];
    #pragma unroll
    for (int t4 = 0; t4 < 4; t4++) {
      av[t4] = *(const bf16x8*)(As + cb + aOff[t4]);
      bv[t4] = *(const bf16x8*)(Bs + cb + bOff[t4]);
    }
    #pragma unroll
    for (int ct = 0; ct < 4; ct++)
      #pragma unroll
      for (int rt = 0; rt < 4; rt++)
        acc[rt][ct] = __builtin_amdgcn_mfma_f32_16x16x32_bf16(av[rt], bv[ct], acc[rt][ct], 0, 0, 0);
    asm volatile("s_waitcnt lgkmcnt(0)" ::: "memory");
    __builtin_amdgcn_sched_barrier(0);
    asm volatile("s_barrier" ::: "memory");
    cur = (cur == 2) ? 0 : cur + 1;
  }
}

// ---------- dual GEMM dispatch: value GEMM (bf16 out) + offaw GEMM (f32) ----
__global__ __launch_bounds__(256, 3) void gemm_dual_kernel(
    const short* __restrict__ A0, const short* __restrict__ W0,
    const float* __restrict__ b0, short* __restrict__ C0,
    const short* __restrict__ A1, const short* __restrict__ W1,
    const float* __restrict__ b1, float* __restrict__ C1) {
  __shared__ __align__(16) short As[3 * 128 * 32];
  __shared__ __align__(16) short Bs[3 * 128 * 32];
  const int id = blockIdx.x;
  const int swz = (id & 7) * 316 + (id >> 3);
  const bool isval = swz < 2016;
  const short* A; const short* Wt; const float* bias;
  int row0, n0;
  if (isval) {
    A = A0; Wt = W0; bias = b0;
    n0 = (swz % 3) * 128; row0 = (swz / 3) * 128;
  } else {
    const int o = swz - 2016;
    A = A1; Wt = W1; bias = b1;
    n0 = (o & 3) * 128; row0 = (o >> 2) * 128;
  }
  const int lane = threadIdx.x & 63, wave = threadIdx.x >> 6;
  const int lr = lane & 15, quad = lane >> 4;
  const int wm = wave >> 1, wn = wave & 1;

  for (int rep = 0; rep < DUAL_REPS; ++rep) {
    f32x4 acc[4][4];
    gemm_core(A, Wt, 768, row0, n0, As, Bs, acc);
    #pragma unroll
    for (int ct = 0; ct < 4; ct++) {
      const int n = n0 + wn * 64 + ct * 16 + lr;
      const float bs = bias[n];
      #pragma unroll
      for (int rt = 0; rt < 4; rt++) {
        #pragma unroll
        for (int i = 0; i < 4; i++) {
          const int m = row0 + wm * 64 + rt * 16 + quad * 4 + i;
          const float v = acc[rt][ct][i] + bs;
          if (isval) C0[(size_t)m * 384 + n] = f2bf(v);
          else       C1[(size_t)m * 512 + n] = v;
        }
      }
    }
  }
}

// ---------- final GEMM: out = q + gamma * (obuf @ w_out + b_out) ----------
__global__ __launch_bounds__(256, 3) void gemm_final_kernel(
    const short* __restrict__ A, const short* __restrict__ Wt,
    const float* __restrict__ bias, const float* __restrict__ qres,
    const float* __restrict__ gamma, float* __restrict__ Cout) {
  __shared__ __align__(16) short As[3 * 128 * 32];
  __shared__ __align__(16) short Bs[3 * 128 * 32];
  const int id = blockIdx.x;
  const int swz = (id & 7) * 96 + (id >> 3);
  const int n0 = (swz % 6) * 128, row0 = (swz / 6) * 128;
  const int lane = threadIdx.x & 63, wave = threadIdx.x >> 6;
  const int lr = lane & 15, quad = lane >> 4;
  const int wm = wave >> 1, wn = wave & 1;

  for (int rep = 0; rep < FIN_REPS; ++rep) {
    f32x4 acc[4][4];
    gemm_core(A, Wt, 384, row0, n0, As, Bs, acc);
    #pragma unroll
    for (int ct = 0; ct < 4; ct++) {
      const int n = n0 + wn * 64 + ct * 16 + lr;
      const float bs = bias[n];
      const float gm = gamma[n];
      #pragma unroll
      for (int rt = 0; rt < 4; rt++) {
        #pragma unroll
        for (int i = 0; i < 4; i++) {
          const int m = row0 + wm * 64 + rt * 16 + quad * 4 + i;
          Cout[(size_t)m * 768 + n] =
              qres[(size_t)m * 768 + n] + gm * (acc[rt][ct][i] + bs);
        }
      }
    }
  }
}

// ---------- sampler: two-phase (LDS geometry) bilinear gather ----------
__global__ __launch_bounds__(384) void sampler_kernel(
    const float* __restrict__ offaw,  // [16384][512]
    const float* __restrict__ refp,   // [B][LQ][3][2]
    const short* __restrict__ value,  // bf16 [B*5376][384]
    short* __restrict__ o) {          // bf16 [16384][384]
  const int tid = threadIdx.x;
  const int blk = (blockIdx.x & 7) * 512 + (blockIdx.x >> 3);  // XCD-chunked
  const int bq0 = blk * 4;
  __shared__ __align__(16) float s[4][440];
  __shared__ float sref[4][6];
  __shared__ float snw[48][12];
  __shared__ __align__(8) ushort4 slin[576];
  __shared__ __align__(16) float4 sw[576];

  for (int rep = 0; rep < SAMP_REPS; ++rep) {
    asm volatile("" ::: "memory");  // prevent cross-rep load hoisting
    {
      const int qi = tid / 96, t = tid % 96;
      const float* row = offaw + (size_t)(bq0 + qi) * 512;
      #pragma unroll
      for (int i = t; i < 108; i += 96)
        *(float4*)&s[qi][i * 4] = *(const float4*)&row[i * 4];
      if (t < 6) sref[qi][t] = refp[(size_t)(bq0 + qi) * 6 + t];
    }
    __syncthreads();

    if (tid < 48) {
      const int qi = tid / 12, h = tid % 12;
      const float* awp = &s[qi][288 + h * 12];
      float mx = awp[0];
      #pragma unroll
      for (int j = 1; j < 12; j++) mx = fmaxf(mx, awp[j]);
      float e[12], ssum = 0.f;
      #pragma unroll
      for (int j = 0; j < 12; j++) { e[j] = __expf(awp[j] - mx); ssum += e[j]; }
      const float inv = 1.f / ssum;
      #pragma unroll
      for (int j = 0; j < 12; j++) snw[tid][j] = e[j] * inv;
    }
    for (int tu = tid; tu < 576; tu += 384) {
      const int qi = tu / 144, rem = tu % 144;
      const int h = rem / 12, lp = rem % 12, l = lp >> 2, p = lp & 3;
      const int Wi = 64 >> l;
      const float Wf = (float)Wi;
      const float rx = sref[qi][l * 2], ry = sref[qi][l * 2 + 1];
      const int oi = ((h * 3 + l) * 4 + p) * 2;
      float x = fmaf(rx, Wf, s[qi][oi] - 0.5f);
      float y = fmaf(ry, Wf, s[qi][oi + 1] - 0.5f);
      float xf = floorf(x), yf = floorf(y);
      float dx = x - xf, dy = y - yf;
      int x0 = (int)xf, y0 = (int)yf;
      int x1 = x0 + 1, y1 = y0 + 1;
      int x0c = min(max(x0, 0), Wi - 1), x1c = min(max(x1, 0), Wi - 1);
      int y0c = min(max(y0, 0), Wi - 1), y1c = min(max(y1, 0), Wi - 1);
      float wx0 = (x0 >= 0 && x0 < Wi) ? (1.f - dx) : 0.f;
      float wx1 = (x1 < Wi && x1 >= 0) ? dx : 0.f;
      float wy0 = (y0 >= 0 && y0 < Wi) ? (1.f - dy) : 0.f;
      float wy1 = (y1 < Wi && y1 >= 0) ? dy : 0.f;
      const int st = (l == 0) ? 0 : (l == 1 ? 4096 : 5120);
      ushort4 lv;
      lv.x = (unsigned short)(st + y0c * Wi + x0c);
      lv.y = (unsigned short)(st + y0c * Wi + x1c);
      lv.z = (unsigned short)(st + y1c * Wi + x0c);
      lv.w = (unsigned short)(st + y1c * Wi + x1c);
      slin[tu] = lv;
      sw[tu] = make_float4(wx0 * wy0, wx1 * wy0, wx0 * wy1, wx1 * wy1);
    }
    __syncthreads();

    {
      const int qi = tid / 96, t = tid % 96;
      const int head = t >> 3, ln4 = t & 7;
      const int bq = bq0 + qi;
      const int b = bq >> 10;
      const unsigned short* vb =
          (const unsigned short*)value + (size_t)b * 5376 * 384 + head * 32 + ln4 * 4;
      float4 acc = make_float4(0.f, 0.f, 0.f, 0.f);
      const int tub = qi * 144 + head * 12;
      const float* nwp = snw[qi * 12 + head];
      #pragma unroll
      for (int lp = 0; lp < 12; lp++) {
        const int tu = tub + lp;
        const float g = nwp[lp];
        const ushort4 lv = slin[tu];
        const float4 wv = sw[tu];
        const ushort4 u00 = *(const ushort4*)(vb + (size_t)lv.x * 384);
        const ushort4 u01 = *(const ushort4*)(vb + (size_t)lv.y * 384);
        const ushort4 u10 = *(const ushort4*)(vb + (size_t)lv.z * 384);
        const ushort4 u11 = *(const ushort4*)(vb + (size_t)lv.w * 384);
        const float w00 = g * wv.x, w01 = g * wv.y, w10 = g * wv.z, w11 = g * wv.w;
        acc.x += w00 * bf2f(u00.x) + w01 * bf2f(u01.x) + w10 * bf2f(u10.x) + w11 * bf2f(u11.x);
        acc.y += w00 * bf2f(u00.y) + w01 * bf2f(u01.y) + w10 * bf2f(u10.y) + w11 * bf2f(u11.y);
        acc.z += w00 * bf2f(u00.z) + w01 * bf2f(u01.z) + w10 * bf2f(u10.z) + w11 * bf2f(u11.z);
        acc.w += w00 * bf2f(u00.w) + w01 * bf2f(u01.w) + w10 * bf2f(u10.w) + w11 * bf2f(u11.w);
      }
      ushort4 outv;
      outv.x = (unsigned short)f2bf(acc.x);
      outv.y = (unsigned short)f2bf(acc.y);
      outv.z = (unsigned short)f2bf(acc.z);
      outv.w = (unsigned short)f2bf(acc.w);
      *(ushort4*)((unsigned short*)o + (size_t)bq * 384 + head * 32 + ln4 * 4) = outv;
    }
    __syncthreads();  // protect s[]/snw/slin/sw before next rep's rewrite
  }
}

// ---------- launch ----------
extern "C" void kernel_launch(void* const* d_in, const int* in_sizes, int n_in,
                              void* d_out, int out_size, void* d_ws, size_t ws_size,
                              hipStream_t stream) {
  (void)in_sizes; (void)n_in; (void)out_size; (void)ws_size;
  const float* q     = (const float*)d_in[0];
  const float* refp  = (const float*)d_in[1];
  const float* kv    = (const float*)d_in[2];
  const float* ln1w  = (const float*)d_in[5];
  const float* ln1b  = (const float*)d_in[6];
  const float* ln2w  = (const float*)d_in[7];
  const float* ln2b  = (const float*)d_in[8];
  const float* gamma = (const float*)d_in[9];
  const float* w_off = (const float*)d_in[10];
  const float* b_off = (const float*)d_in[11];
  const float* w_aw  = (const float*)d_in[12];
  const float* b_aw  = (const float*)d_in[13];
  const float* w_val = (const float*)d_in[14];
  const float* b_val = (const float*)d_in[15];
  const float* w_out = (const float*)d_in[16];
  const float* b_out = (const float*)d_in[17];
  float* out = (float*)d_out;

  char* wsp = (char*)d_ws;
  size_t cur = 0;
  auto alloc = [&](size_t bytes) -> void* {
    cur = (cur + 255) & ~(size_t)255;
    void* p = wsp + cur;
    cur += bytes;
    return p;
  };
  short*  wT_val   = (short*)alloc((size_t)384 * 768 * 2);
  short*  wT_offaw = (short*)alloc((size_t)512 * 768 * 2);
  short*  wT_out   = (short*)alloc((size_t)768 * 384 * 2);
  float*  bias_cat = (float*)alloc((size_t)512 * 4);
  short*  kvn      = (short*)alloc((size_t)86016 * 768 * 2);
  short*  qn       = (short*)alloc((size_t)16384 * 768 * 2);
  short*  value    = (short*)alloc((size_t)86016 * 384 * 2);
  float*  offaw    = (float*)alloc((size_t)16384 * 512 * 4);
  short*  obuf     = (short*)alloc((size_t)16384 * 384 * 2);

  fused_pre_kernel<<<26082, 256, 0, stream>>>(
      kv, q, ln2w, ln2b, ln1w, ln1b, kvn, qn,
      w_val, w_off, w_aw, w_out, b_off, b_aw,
      wT_val, wT_offaw, wT_out, bias_cat);
  gemm_dual_kernel<<<2528, 256, 0, stream>>>(
      kvn, wT_val, b_val, value, qn, wT_offaw, bias_cat, offaw);
  sampler_kernel<<<4096, 384, 0, stream>>>(offaw, refp, value, obuf);
  gemm_final_kernel<<<768, 256, 0, stream>>>(
      obuf, wT_out, b_out, q, gamma, out);
}

// Round 7
// 615.594 us; speedup vs baseline: 2.7039x; 2.7039x over previous
//
#include <hip/hip_runtime.h>

#define DEV __device__ __forceinline__

typedef short bf16x8 __attribute__((ext_vector_type(8)));
typedef short short8 __attribute__((ext_vector_type(8)));
typedef float f32x4 __attribute__((ext_vector_type(4)));
typedef unsigned int u32;
typedef __attribute__((address_space(1))) const u32* gas_ptr;
typedef __attribute__((address_space(3))) u32* las_ptr;

// ---------- helpers ----------
DEV short f2bf(float f) {
  union { float f; unsigned u; } un; un.f = f;
  unsigned r = un.u + 0x7FFFu + ((un.u >> 16) & 1u);  // RNE
  return (short)(r >> 16);
}
DEV float bf2f(unsigned short s) {
  union { unsigned u; float f; } un;
  un.u = ((unsigned)s) << 16;
  return un.f;
}
DEV void gload16(const short* g, short* l) {
  __builtin_amdgcn_global_load_lds((gas_ptr)g, (las_ptr)l, 16, 0, 0);
}
DEV float hsum4(float4 v) { return v.x + v.y + v.z + v.w; }

// ---------- LayerNorm row (wave-per-row, barrier-free) ----------
DEV void ln_row4(const float* __restrict__ x, const float* __restrict__ w,
                 const float* __restrict__ b, short* __restrict__ y,
                 const int rb) {
  const int wv = threadIdx.x >> 6, lane = threadIdx.x & 63;
  const int row = rb * 4 + wv;
  const float* xr = x + (size_t)row * 768;
  float4 v0 = *(const float4*)(xr + lane * 4);
  float4 v1 = *(const float4*)(xr + 256 + lane * 4);
  float4 v2 = *(const float4*)(xr + 512 + lane * 4);
  float s = hsum4(v0) + hsum4(v1) + hsum4(v2);
  #pragma unroll
  for (int off = 32; off > 0; off >>= 1) s += __shfl_xor(s, off, 64);
  const float mu = s * (1.f / 768.f);
  float4 d0 = make_float4(v0.x - mu, v0.y - mu, v0.z - mu, v0.w - mu);
  float4 d1 = make_float4(v1.x - mu, v1.y - mu, v1.z - mu, v1.w - mu);
  float4 d2 = make_float4(v2.x - mu, v2.y - mu, v2.z - mu, v2.w - mu);
  float vs = d0.x * d0.x + d0.y * d0.y + d0.z * d0.z + d0.w * d0.w +
             d1.x * d1.x + d1.y * d1.y + d1.z * d1.z + d1.w * d1.w +
             d2.x * d2.x + d2.y * d2.y + d2.z * d2.z + d2.w * d2.w;
  #pragma unroll
  for (int off = 32; off > 0; off >>= 1) vs += __shfl_xor(vs, off, 64);
  const float rs = rsqrtf(vs * (1.f / 768.f) + 1e-6f);
  const float4 w0 = *(const float4*)(w + lane * 4);
  const float4 w1 = *(const float4*)(w + 256 + lane * 4);
  const float4 w2 = *(const float4*)(w + 512 + lane * 4);
  const float4 b0 = *(const float4*)(b + lane * 4);
  const float4 b1 = *(const float4*)(b + 256 + lane * 4);
  const float4 b2 = *(const float4*)(b + 512 + lane * 4);
  unsigned short* yr = (unsigned short*)y + (size_t)row * 768;
  ushort4 o;
  o.x = (unsigned short)f2bf(d0.x * rs * w0.x + b0.x);
  o.y = (unsigned short)f2bf(d0.y * rs * w0.y + b0.y);
  o.z = (unsigned short)f2bf(d0.z * rs * w0.z + b0.z);
  o.w = (unsigned short)f2bf(d0.w * rs * w0.w + b0.w);
  *(ushort4*)(yr + lane * 4) = o;
  o.x = (unsigned short)f2bf(d1.x * rs * w1.x + b1.x);
  o.y = (unsigned short)f2bf(d1.y * rs * w1.y + b1.y);
  o.z = (unsigned short)f2bf(d1.z * rs * w1.z + b1.z);
  o.w = (unsigned short)f2bf(d1.w * rs * w1.w + b1.w);
  *(ushort4*)(yr + 256 + lane * 4) = o;
  o.x = (unsigned short)f2bf(d2.x * rs * w2.x + b2.x);
  o.y = (unsigned short)f2bf(d2.y * rs * w2.y + b2.y);
  o.z = (unsigned short)f2bf(d2.z * rs * w2.z + b2.z);
  o.w = (unsigned short)f2bf(d2.w * rs * w2.w + b2.w);
  *(ushort4*)(yr + 512 + lane * 4) = o;
}

// ---------- fused pre-kernel: ln_kv + ln_q + weight pack ----------
__global__ __launch_bounds__(256) void fused_pre_kernel(
    const float* __restrict__ kv, const float* __restrict__ q,
    const float* __restrict__ ln2w, const float* __restrict__ ln2b,
    const float* __restrict__ ln1w, const float* __restrict__ ln1b,
    short* __restrict__ kvn, short* __restrict__ qn,
    const float* __restrict__ w_val, const float* __restrict__ w_off,
    const float* __restrict__ w_aw, const float* __restrict__ w_out,
    const float* __restrict__ b_off, const float* __restrict__ b_aw,
    short* __restrict__ wT_val, short* __restrict__ wT_offaw,
    short* __restrict__ wT_out, float* __restrict__ bias_cat) {
  const int bid = blockIdx.x;
  if (bid < 21504) { ln_row4(kv, ln2w, ln2b, kvn, bid); return; }
  if (bid < 25600) { ln_row4(q, ln1w, ln1b, qn, bid - 21504); return; }
  int g = (bid - 25600) * 256 + threadIdx.x;
  bf16x8 v;
  if (g < 36864) {  // wT_val[n*768+k] = w_val[k*384+n]
    int n = g / 96, k0 = (g % 96) * 8;
    #pragma unroll
    for (int i = 0; i < 8; i++) v[i] = f2bf(w_val[(size_t)(k0 + i) * 384 + n]);
    *(bf16x8*)&wT_val[n * 768 + k0] = v;
    return;
  }
  g -= 36864;
  if (g < 27648) {  // wT_offaw rows 0..287 from w_off
    int n = g / 96, k0 = (g % 96) * 8;
    #pragma unroll
    for (int i = 0; i < 8; i++) v[i] = f2bf(w_off[(size_t)(k0 + i) * 288 + n]);
    *(bf16x8*)&wT_offaw[n * 768 + k0] = v;
    return;
  }
  g -= 27648;
  if (g < 13824) {  // rows 288..431 from w_aw
    int n = g / 96, k0 = (g % 96) * 8;
    #pragma unroll
    for (int i = 0; i < 8; i++) v[i] = f2bf(w_aw[(size_t)(k0 + i) * 144 + n]);
    *(bf16x8*)&wT_offaw[(288 + n) * 768 + k0] = v;
    return;
  }
  g -= 13824;
  if (g < 7680) {  // rows 432..511 zero
    int n = 432 + g / 96, k0 = (g % 96) * 8;
    #pragma unroll
    for (int i = 0; i < 8; i++) v[i] = 0;
    *(bf16x8*)&wT_offaw[n * 768 + k0] = v;
    return;
  }
  g -= 7680;
  if (g < 36864) {  // wT_out[n*384+k] = w_out[k*768+n]
    int n = g / 48, k0 = (g % 48) * 8;
    #pragma unroll
    for (int i = 0; i < 8; i++) v[i] = f2bf(w_out[(size_t)(k0 + i) * 768 + n]);
    *(bf16x8*)&wT_out[n * 384 + k0] = v;
    return;
  }
  g -= 36864;
  if (g < 512) { bias_cat[g] = (g < 288) ? b_off[g] : (g < 432 ? b_aw[g - 288] : 0.f); }
}

// ---------- GEMM core: 128x128 tile, BK=32, 3-deep LDS pipeline ----------
// (R5-proven: XOR-swizzled LDS, vmcnt(8) steady state, lgkmcnt(0)+sched_barrier
// before barrier2 to close the async-LDS-DMA overwrite race)
DEV void gemm_core(const short* __restrict__ A, const short* __restrict__ Wt,
                   const int K, const int row0, const int n0,
                   short* As, short* Bs, f32x4 acc[4][4]) {
  const int tid = threadIdx.x;
  const int wave = tid >> 6, lane = tid & 63;
  const int lr = lane & 15, quad = lane >> 4;
  const int wm = wave >> 1, wn = wave & 1;

  const short* gA[2]; const short* gB[2];
  int loA[2];
  #pragma unroll
  for (int rnd = 0; rnd < 2; rnd++) {
    int G = rnd * 256 + wave * 64 + lane;
    int line = G >> 3, pos = G & 7, x = pos ^ (line & 7);
    int r = line * 2 + (x >> 2), qk = (x & 3) * 8;
    gA[rnd] = A + (size_t)(row0 + r) * K + qk;
    gB[rnd] = Wt + (size_t)(n0 + r) * K + qk;
    loA[rnd] = (rnd * 256 + wave * 64) * 8;
  }

  int aOff[4], bOff[4];
  #pragma unroll
  for (int t4 = 0; t4 < 4; t4++) {
    int r = wm * 64 + t4 * 16 + lr;
    int pos = ((r & 1) * 4 + quad) ^ ((r >> 1) & 7);
    aOff[t4] = ((r >> 1) * 8 + pos) * 8;
    int rb = wn * 64 + t4 * 16 + lr;
    int posb = ((rb & 1) * 4 + quad) ^ ((rb >> 1) & 7);
    bOff[t4] = ((rb >> 1) * 8 + posb) * 8;
  }

  #pragma unroll
  for (int i = 0; i < 4; i++)
    #pragma unroll
    for (int j = 0; j < 4; j++)
      #pragma unroll
      for (int e = 0; e < 4; e++) acc[i][j][e] = 0.f;

  const int nt = K >> 5;
  #pragma unroll
  for (int pb = 0; pb < 2; pb++) {
    const int bb = pb * 4096;
    gload16(gA[0], As + bb + loA[0]);
    gload16(gA[1], As + bb + loA[1]);
    gload16(gB[0], Bs + bb + loA[0]);
    gload16(gB[1], Bs + bb + loA[1]);
    gA[0] += 32; gA[1] += 32; gB[0] += 32; gB[1] += 32;
  }

  int cur = 0;
  for (int t = 0; t < nt; ++t) {
    if (t + 2 < nt) {
      const int nb = (cur == 0 ? 2 : cur - 1) * 4096;  // (cur+2)%3
      gload16(gA[0], As + nb + loA[0]);
      gload16(gA[1], As + nb + loA[1]);
      gload16(gB[0], Bs + nb + loA[0]);
      gload16(gB[1], Bs + nb + loA[1]);
      gA[0] += 32; gA[1] += 32; gB[0] += 32; gB[1] += 32;
      asm volatile("s_waitcnt vmcnt(8)" ::: "memory");
    } else if (t + 1 < nt) {
      asm volatile("s_waitcnt vmcnt(4)" ::: "memory");
    } else {
      asm volatile("s_waitcnt vmcnt(0)" ::: "memory");
    }
    asm volatile("s_barrier" ::: "memory");
    const int cb = cur * 4096;
    bf16x8 av[4], bv[4];
    #pragma unroll
    for (int t4 = 0; t4 < 4; t4++) {
      av[t4] = *(const bf16x8*)(As + cb + aOff[t4]);
      bv[t4] = *(const bf16x8*)(Bs + cb + bOff[t4]);
    }
    #pragma unroll
    for (int ct = 0; ct < 4; ct++)
      #pragma unroll
      for (int rt = 0; rt < 4; rt++)
        acc[rt][ct] = __builtin_amdgcn_mfma_f32_16x16x32_bf16(av[rt], bv[ct], acc[rt][ct], 0, 0, 0);
    asm volatile("s_waitcnt lgkmcnt(0)" ::: "memory");
    __builtin_amdgcn_sched_barrier(0);
    asm volatile("s_barrier" ::: "memory");
    cur = (cur == 2) ? 0 : cur + 1;
  }
}

// ---------- LDS-transpose epilogues: coalesced float4 / short8 C-writes ----
// Two phases of 64 rows. Write: acc scalars -> padded LDS (<=2-way bank = free).
// Read: 256 threads row-major -> full-line global stores (+ residual fusion).
template <bool RES>
DEV void epilogue_f32(float* lds, f32x4 acc[4][4], const float* __restrict__ bias,
                      const float* __restrict__ qres, const float* __restrict__ gamma,
                      float* __restrict__ Cout, const int N,
                      const int row0, const int n0) {
  const int tid = threadIdx.x, wave = tid >> 6, lane = tid & 63;
  const int lr = lane & 15, quad = lane >> 4;
  const int wm = wave >> 1, wn = wave & 1;
  const int ST = 132;  // floats; (4r+c)%32 banks: quads collide only 2-way
  #pragma unroll
  for (int ph = 0; ph < 2; ++ph) {
    __syncthreads();
    if (wm == ph) {
      #pragma unroll
      for (int ct = 0; ct < 4; ct++)
        #pragma unroll
        for (int rt = 0; rt < 4; rt++)
          #pragma unroll
          for (int i = 0; i < 4; i++)
            lds[(rt * 16 + quad * 4 + i) * ST + wn * 64 + ct * 16 + lr] = acc[rt][ct][i];
    }
    __syncthreads();
    #pragma unroll
    for (int it = 0; it < 8; ++it) {
      const int slot = it * 256 + tid;       // 2048 = 64 rows x 32 col4
      const int r = slot >> 5, c4 = slot & 31;
      const float4 v = *(float4*)&lds[r * ST + c4 * 4];
      const int m = row0 + ph * 64 + r, n = n0 + c4 * 4;
      const float4 bs = *(const float4*)&bias[n];
      float4 o;
      if (RES) {
        const float4 qv = *(const float4*)&qres[(size_t)m * N + n];
        const float4 gm = *(const float4*)&gamma[n];
        o.x = qv.x + gm.x * (v.x + bs.x);
        o.y = qv.y + gm.y * (v.y + bs.y);
        o.z = qv.z + gm.z * (v.z + bs.z);
        o.w = qv.w + gm.w * (v.w + bs.w);
      } else {
        o.x = v.x + bs.x; o.y = v.y + bs.y; o.z = v.z + bs.z; o.w = v.w + bs.w;
      }
      *(float4*)&Cout[(size_t)m * N + n] = o;
    }
  }
}

DEV void epilogue_bf16(unsigned short* lds, f32x4 acc[4][4],
                       const float* __restrict__ bias,
                       unsigned short* __restrict__ Cout, const int N,
                       const int row0, const int n0) {
  const int tid = threadIdx.x, wave = tid >> 6, lane = tid & 63;
  const int lr = lane & 15, quad = lane >> 4;
  const int wm = wave >> 1, wn = wave & 1;
  const int ST = 136;  // ushorts; 16B-aligned rows; writes 2-way, reads ~2-way
  #pragma unroll
  for (int ph = 0; ph < 2; ++ph) {
    __syncthreads();
    if (wm == ph) {
      #pragma unroll
      for (int ct = 0; ct < 4; ct++) {
        const float bs = bias[n0 + wn * 64 + ct * 16 + lr];
        #pragma unroll
        for (int rt = 0; rt < 4; rt++)
          #pragma unroll
          for (int i = 0; i < 4; i++)
            lds[(rt * 16 + quad * 4 + i) * ST + wn * 64 + ct * 16 + lr] =
                (unsigned short)f2bf(acc[rt][ct][i] + bs);
      }
    }
    __syncthreads();
    #pragma unroll
    for (int it = 0; it < 4; ++it) {
      const int slot = it * 256 + tid;       // 1024 = 64 rows x 16 col8
      const int r = slot >> 4, c8 = slot & 15;
      const short8 v = *(short8*)&lds[r * ST + c8 * 8];
      const int m = row0 + ph * 64 + r;
      *(short8*)&Cout[(size_t)m * N + n0 + c8 * 8] = v;
    }
  }
}

// ---------- dual GEMM dispatch: value GEMM (bf16 out) + offaw GEMM (f32) ----
__global__ __launch_bounds__(256, 3) void gemm_dual_kernel(
    const short* __restrict__ A0, const short* __restrict__ W0,
    const float* __restrict__ b0, short* __restrict__ C0,
    const short* __restrict__ A1, const short* __restrict__ W1,
    const float* __restrict__ b1, float* __restrict__ C1) {
  __shared__ __align__(16) char smem[49152];
  short* As = (short*)smem;
  short* Bs = (short*)(smem + 24576);
  const int id = blockIdx.x;
  const int swz = (id & 7) * 316 + (id >> 3);
  const bool isval = swz < 2016;
  const short* A; const short* Wt; const float* bias;
  int row0, n0;
  if (isval) {
    A = A0; Wt = W0; bias = b0;
    n0 = (swz % 3) * 128; row0 = (swz / 3) * 128;
  } else {
    const int o = swz - 2016;
    A = A1; Wt = W1; bias = b1;
    n0 = (o & 3) * 128; row0 = (o >> 2) * 128;
  }
  f32x4 acc[4][4];
  gemm_core(A, Wt, 768, row0, n0, As, Bs, acc);
  if (isval) {
    epilogue_bf16((unsigned short*)smem, acc, bias, (unsigned short*)C0, 384, row0, n0);
  } else {
    epilogue_f32<false>((float*)smem, acc, bias, nullptr, nullptr, C1, 512, row0, n0);
  }
}

// ---------- final GEMM: out = q + gamma * (obuf @ w_out + b_out) ----------
__global__ __launch_bounds__(256, 3) void gemm_final_kernel(
    const short* __restrict__ A, const short* __restrict__ Wt,
    const float* __restrict__ bias, const float* __restrict__ qres,
    const float* __restrict__ gamma, float* __restrict__ Cout) {
  __shared__ __align__(16) char smem[49152];
  short* As = (short*)smem;
  short* Bs = (short*)(smem + 24576);
  const int id = blockIdx.x;
  const int swz = (id & 7) * 96 + (id >> 3);
  const int n0 = (swz % 6) * 128, row0 = (swz / 6) * 128;
  f32x4 acc[4][4];
  gemm_core(A, Wt, 384, row0, n0, As, Bs, acc);
  epilogue_f32<true>((float*)smem, acc, bias, qres, gamma, Cout, 768, row0, n0);
}

// ---------- sampler: two-phase (LDS geometry) bilinear gather ----------
__global__ __launch_bounds__(384) void sampler_kernel(
    const float* __restrict__ offaw,  // [16384][512]
    const float* __restrict__ refp,   // [B][LQ][3][2]
    const short* __restrict__ value,  // bf16 [B*5376][384]
    short* __restrict__ o) {          // bf16 [16384][384]
  const int tid = threadIdx.x;
  const int blk = (blockIdx.x & 7) * 512 + (blockIdx.x >> 3);  // XCD-chunked
  const int bq0 = blk * 4;
  __shared__ __align__(16) float s[4][440];
  __shared__ float sref[4][6];
  __shared__ float snw[48][12];
  __shared__ __align__(8) ushort4 slin[576];
  __shared__ __align__(16) float4 sw[576];

  {
    const int qi = tid / 96, t = tid % 96;
    const float* row = offaw + (size_t)(bq0 + qi) * 512;
    #pragma unroll
    for (int i = t; i < 108; i += 96)
      *(float4*)&s[qi][i * 4] = *(const float4*)&row[i * 4];
    if (t < 6) sref[qi][t] = refp[(size_t)(bq0 + qi) * 6 + t];
  }
  __syncthreads();

  if (tid < 48) {
    const int qi = tid / 12, h = tid % 12;
    const float* awp = &s[qi][288 + h * 12];
    float mx = awp[0];
    #pragma unroll
    for (int j = 1; j < 12; j++) mx = fmaxf(mx, awp[j]);
    float e[12], ssum = 0.f;
    #pragma unroll
    for (int j = 0; j < 12; j++) { e[j] = __expf(awp[j] - mx); ssum += e[j]; }
    const float inv = 1.f / ssum;
    #pragma unroll
    for (int j = 0; j < 12; j++) snw[tid][j] = e[j] * inv;
  }
  for (int tu = tid; tu < 576; tu += 384) {
    const int qi = tu / 144, rem = tu % 144;
    const int h = rem / 12, lp = rem % 12, l = lp >> 2, p = lp & 3;
    const int Wi = 64 >> l;
    const float Wf = (float)Wi;
    const float rx = sref[qi][l * 2], ry = sref[qi][l * 2 + 1];
    const int oi = ((h * 3 + l) * 4 + p) * 2;
    float x = fmaf(rx, Wf, s[qi][oi] - 0.5f);
    float y = fmaf(ry, Wf, s[qi][oi + 1] - 0.5f);
    float xf = floorf(x), yf = floorf(y);
    float dx = x - xf, dy = y - yf;
    int x0 = (int)xf, y0 = (int)yf;
    int x1 = x0 + 1, y1 = y0 + 1;
    int x0c = min(max(x0, 0), Wi - 1), x1c = min(max(x1, 0), Wi - 1);
    int y0c = min(max(y0, 0), Wi - 1), y1c = min(max(y1, 0), Wi - 1);
    float wx0 = (x0 >= 0 && x0 < Wi) ? (1.f - dx) : 0.f;
    float wx1 = (x1 < Wi && x1 >= 0) ? dx : 0.f;
    float wy0 = (y0 >= 0 && y0 < Wi) ? (1.f - dy) : 0.f;
    float wy1 = (y1 < Wi && y1 >= 0) ? dy : 0.f;
    const int st = (l == 0) ? 0 : (l == 1 ? 4096 : 5120);
    ushort4 lv;
    lv.x = (unsigned short)(st + y0c * Wi + x0c);
    lv.y = (unsigned short)(st + y0c * Wi + x1c);
    lv.z = (unsigned short)(st + y1c * Wi + x0c);
    lv.w = (unsigned short)(st + y1c * Wi + x1c);
    slin[tu] = lv;
    sw[tu] = make_float4(wx0 * wy0, wx1 * wy0, wx0 * wy1, wx1 * wy1);
  }
  __syncthreads();

  const int qi = tid / 96, t = tid % 96;
  const int head = t >> 3, ln4 = t & 7;
  const int bq = bq0 + qi;
  const int b = bq >> 10;
  const unsigned short* vb =
      (const unsigned short*)value + (size_t)b * 5376 * 384 + head * 32 + ln4 * 4;
  float4 acc = make_float4(0.f, 0.f, 0.f, 0.f);
  const int tub = qi * 144 + head * 12;
  const float* nwp = snw[qi * 12 + head];
  #pragma unroll
  for (int lp = 0; lp < 12; lp++) {
    const int tu = tub + lp;
    const float g = nwp[lp];
    const ushort4 lv = slin[tu];
    const float4 wv = sw[tu];
    const ushort4 u00 = *(const ushort4*)(vb + (size_t)lv.x * 384);
    const ushort4 u01 = *(const ushort4*)(vb + (size_t)lv.y * 384);
    const ushort4 u10 = *(const ushort4*)(vb + (size_t)lv.z * 384);
    const ushort4 u11 = *(const ushort4*)(vb + (size_t)lv.w * 384);
    const float w00 = g * wv.x, w01 = g * wv.y, w10 = g * wv.z, w11 = g * wv.w;
    acc.x += w00 * bf2f(u00.x) + w01 * bf2f(u01.x) + w10 * bf2f(u10.x) + w11 * bf2f(u11.x);
    acc.y += w00 * bf2f(u00.y) + w01 * bf2f(u01.y) + w10 * bf2f(u10.y) + w11 * bf2f(u11.y);
    acc.z += w00 * bf2f(u00.z) + w01 * bf2f(u01.z) + w10 * bf2f(u10.z) + w11 * bf2f(u11.z);
    acc.w += w00 * bf2f(u00.w) + w01 * bf2f(u01.w) + w10 * bf2f(u10.w) + w11 * bf2f(u11.w);
  }
  ushort4 outv;
  outv.x = (unsigned short)f2bf(acc.x);
  outv.y = (unsigned short)f2bf(acc.y);
  outv.z = (unsigned short)f2bf(acc.z);
  outv.w = (unsigned short)f2bf(acc.w);
  *(ushort4*)((unsigned short*)o + (size_t)bq * 384 + head * 32 + ln4 * 4) = outv;
}

// ---------- launch ----------
extern "C" void kernel_launch(void* const* d_in, const int* in_sizes, int n_in,
                              void* d_out, int out_size, void* d_ws, size_t ws_size,
                              hipStream_t stream) {
  (void)in_sizes; (void)n_in; (void)out_size; (void)ws_size;
  const float* q     = (const float*)d_in[0];
  const float* refp  = (const float*)d_in[1];
  const float* kv    = (const float*)d_in[2];
  const float* ln1w  = (const float*)d_in[5];
  const float* ln1b  = (const float*)d_in[6];
  const float* ln2w  = (const float*)d_in[7];
  const float* ln2b  = (const float*)d_in[8];
  const float* gamma = (const float*)d_in[9];
  const float* w_off = (const float*)d_in[10];
  const float* b_off = (const float*)d_in[11];
  const float* w_aw  = (const float*)d_in[12];
  const float* b_aw  = (const float*)d_in[13];
  const float* w_val = (const float*)d_in[14];
  const float* b_val = (const float*)d_in[15];
  const float* w_out = (const float*)d_in[16];
  const float* b_out = (const float*)d_in[17];
  float* out = (float*)d_out;

  char* wsp = (char*)d_ws;
  size_t cur = 0;
  auto alloc = [&](size_t bytes) -> void* {
    cur = (cur + 255) & ~(size_t)255;
    void* p = wsp + cur;
    cur += bytes;
    return p;
  };
  short*  wT_val   = (short*)alloc((size_t)384 * 768 * 2);
  short*  wT_offaw = (short*)alloc((size_t)512 * 768 * 2);
  short*  wT_out   = (short*)alloc((size_t)768 * 384 * 2);
  float*  bias_cat = (float*)alloc((size_t)512 * 4);
  short*  kvn      = (short*)alloc((size_t)86016 * 768 * 2);
  short*  qn       = (short*)alloc((size_t)16384 * 768 * 2);
  short*  value    = (short*)alloc((size_t)86016 * 384 * 2);
  float*  offaw    = (float*)alloc((size_t)16384 * 512 * 4);
  short*  obuf     = (short*)alloc((size_t)16384 * 384 * 2);

  fused_pre_kernel<<<26082, 256, 0, stream>>>(
      kv, q, ln2w, ln2b, ln1w, ln1b, kvn, qn,
      w_val, w_off, w_aw, w_out, b_off, b_aw,
      wT_val, wT_offaw, wT_out, bias_cat);
  gemm_dual_kernel<<<2528, 256, 0, stream>>>(
      kvn, wT_val, b_val, value, qn, wT_offaw, bias_cat, offaw);
  sampler_kernel<<<4096, 384, 0, stream>>>(offaw, refp, value, obuf);
  gemm_final_kernel<<<768, 256, 0, stream>>>(
      obuf, wT_out, b_out, q, gamma, out);
}